// Round 1
// baseline (227.958 us; speedup 1.0000x reference)
//
#include <hip/hip_runtime.h>

#define T_TOK 200
#define EMB   128
#define S_TILE 16

// ---------------- Pooling: one block per sample ----------------
// Block = 256 threads = 4 waves. Each wave loads complete embedding rows
// (128 floats) as float2 per lane (64 lanes * 8B = 512B, fully coalesced).
// Waves take tokens t = wid, wid+4, wid+8, ... ; LDS reduce across waves.
__global__ __launch_bounds__(256) void pool_kernel(
    const int* __restrict__ x, const int* __restrict__ lengths,
    const float* __restrict__ emb, float* __restrict__ pooled)
{
    const int n    = blockIdx.x;
    const int tid  = threadIdx.x;
    const int wid  = tid >> 6;
    const int lane = tid & 63;

    const int len = lengths[n];
    const int* xr = x + (size_t)n * T_TOK;

    float ax = 0.f, ay = 0.f;
    int t = wid;
    // 2x unroll: two independent idx->row load chains in flight
    for (; t + 4 < len; t += 8) {
        int i0 = xr[t];
        int i1 = xr[t + 4];
        const float2* r0 = (const float2*)(emb + (size_t)i0 * EMB);
        const float2* r1 = (const float2*)(emb + (size_t)i1 * EMB);
        float2 v0 = r0[lane];
        float2 v1 = r1[lane];
        ax += v0.x + v1.x;
        ay += v0.y + v1.y;
    }
    if (t < len) {
        int i0 = xr[t];
        const float2* r0 = (const float2*)(emb + (size_t)i0 * EMB);
        float2 v0 = r0[lane];
        ax += v0.x;
        ay += v0.y;
    }

    __shared__ float sh[4][EMB];
    sh[wid][2 * lane]     = ax;
    sh[wid][2 * lane + 1] = ay;
    __syncthreads();

    if (tid < EMB) {
        float s = sh[0][tid] + sh[1][tid] + sh[2][tid] + sh[3][tid];
        pooled[(size_t)n * EMB + tid] = s / (float)len;
    }
}

// ---------------- Fused MLP: 16 samples per block ----------------
// Activations live in LDS with +4-float padded row stride (bank-conflict
// free). Each thread owns OPT consecutive output columns for SPT samples;
// weights stream from global (L2-resident, 900KB total), activations are
// wave-uniform LDS broadcasts.
#define LPAD 4

template <int FIN, int FOUT, bool RELU>
__device__ __forceinline__ void layer(const float* __restrict__ sin,
                                      float* __restrict__ sout,
                                      const float* __restrict__ W,
                                      const float* __restrict__ b, int tid)
{
    constexpr int SIN_STR  = FIN + LPAD;
    constexpr int SOUT_STR = FOUT + LPAD;
    constexpr int OPT    = (FOUT > 256) ? (FOUT / 256) : 1; // out cols / thread
    constexpr int NO     = FOUT / OPT;                      // threads per sample-group
    constexpr int GROUPS = 256 / NO;
    constexpr int SPT    = S_TILE / GROUPS;                 // samples / thread

    const int o0 = (tid % NO) * OPT;
    const int s0 = (tid / NO) * SPT;

    float acc[OPT][SPT];
#pragma unroll
    for (int i = 0; i < OPT; ++i) {
        float bi = b[o0 + i];
#pragma unroll
        for (int j = 0; j < SPT; ++j) acc[i][j] = bi;
    }

    const float* wrow[OPT];
#pragma unroll
    for (int i = 0; i < OPT; ++i) wrow[i] = W + (size_t)(o0 + i) * FIN;

    for (int f = 0; f < FIN; f += 4) {
        float4 w[OPT];
#pragma unroll
        for (int i = 0; i < OPT; ++i)
            w[i] = *(const float4*)(wrow[i] + f);
#pragma unroll
        for (int j = 0; j < SPT; ++j) {
            float4 xv = *(const float4*)&sin[(s0 + j) * SIN_STR + f];
#pragma unroll
            for (int i = 0; i < OPT; ++i) {
                acc[i][j] = fmaf(xv.x, w[i].x, acc[i][j]);
                acc[i][j] = fmaf(xv.y, w[i].y, acc[i][j]);
                acc[i][j] = fmaf(xv.z, w[i].z, acc[i][j]);
                acc[i][j] = fmaf(xv.w, w[i].w, acc[i][j]);
            }
        }
    }

#pragma unroll
    for (int j = 0; j < SPT; ++j) {
#pragma unroll
        for (int i = 0; i < OPT; ++i) {
            float v = acc[i][j];
            if (RELU) v = fmaxf(v, 0.f);
            sout[(s0 + j) * SOUT_STR + (o0 + i)] = v;
        }
    }
}

__global__ __launch_bounds__(256) void mlp_kernel(
    const float* __restrict__ pooled,
    const float* __restrict__ W1, const float* __restrict__ b1,
    const float* __restrict__ W2, const float* __restrict__ b2,
    const float* __restrict__ W3, const float* __restrict__ b3,
    const float* __restrict__ W4, const float* __restrict__ b4,
    float* __restrict__ out)
{
    // bufA: X (stride 132, 16*132=2112 floats) then H2 (stride 260, 4160 floats)
    // bufB: H1 (stride 516, 8256 floats) then H3 (stride 132, 2112 floats)
    __shared__ float bufA[S_TILE * (256 + LPAD)];
    __shared__ float bufB[S_TILE * (512 + LPAD)];

    const int tid  = threadIdx.x;
    const int base = blockIdx.x * S_TILE;

    // Load pooled tile into LDS (padded stride 132)
    for (int idx = tid; idx < S_TILE * EMB; idx += 256) {
        int s = idx >> 7;
        int f = idx & 127;
        bufA[s * (EMB + LPAD) + f] = pooled[(size_t)(base + s) * EMB + f];
    }
    __syncthreads();

    layer<128, 512, true>(bufA, bufB, W1, b1, tid);
    __syncthreads();
    layer<512, 256, true>(bufB, bufA, W2, b2, tid);
    __syncthreads();
    layer<256, 128, true>(bufA, bufB, W3, b3, tid);
    __syncthreads();

    // Final layer: 128 -> 2, only 32 outputs per block
    if (tid < 2 * S_TILE) {
        int s = tid >> 1;
        int o = tid & 1;
        float accv = b4[o];
        const float* xr = &bufB[s * (EMB + LPAD)];
        const float* wr = &W4[(size_t)o * EMB];
#pragma unroll 8
        for (int f = 0; f < EMB; ++f) accv = fmaf(xr[f], wr[f], accv);
        out[(size_t)(base + s) * 2 + o] = accv;
    }
}

extern "C" void kernel_launch(void* const* d_in, const int* in_sizes, int n_in,
                              void* d_out, int out_size, void* d_ws, size_t ws_size,
                              hipStream_t stream)
{
    const int*   x       = (const int*)d_in[0];
    const int*   lengths = (const int*)d_in[1];
    const float* emb     = (const float*)d_in[2];
    const float* W1      = (const float*)d_in[3];
    const float* b1      = (const float*)d_in[4];
    const float* W2      = (const float*)d_in[5];
    const float* b2      = (const float*)d_in[6];
    const float* W3      = (const float*)d_in[7];
    const float* b3      = (const float*)d_in[8];
    const float* W4      = (const float*)d_in[9];
    const float* b4      = (const float*)d_in[10];
    float*       out     = (float*)d_out;

    const int N = in_sizes[1];           // 4096
    float* pooled = (float*)d_ws;        // N*128 floats = 2 MB

    pool_kernel<<<N, 256, 0, stream>>>(x, lengths, emb, pooled);
    mlp_kernel<<<N / S_TILE, 256, 0, stream>>>(pooled, W1, b1, W2, b2, W3, b3,
                                               W4, b4, out);
}

// Round 2
// 194.652 us; speedup vs baseline: 1.1711x; 1.1711x over previous
//
#include <hip/hip_runtime.h>

#define T_TOK 200
#define EMB   128
#define S_TILE 8

// ---------------- Pooling: one WAVE per sample ----------------
// Block = 256 threads = 4 waves; wave w handles sample blockIdx.x*4+w.
// Indices for all 200 tokens preloaded into 4 regs/lane, broadcast with
// __shfl -> row loads have no memory dependency; 8 rows (4KB) in flight.
// Each lane accumulates cols {2*lane, 2*lane+1}; direct float2 writeout.
__global__ __launch_bounds__(256) void pool_kernel(
    const int* __restrict__ x, const int* __restrict__ lengths,
    const float* __restrict__ emb, float* __restrict__ pooled)
{
    const int tid  = threadIdx.x;
    const int wid  = tid >> 6;
    const int lane = tid & 63;
    const int n    = blockIdx.x * 4 + wid;

    const int len = lengths[n];
    const int* xr = x + (size_t)n * T_TOK;

    // lane l holds token indices l, 64+l, 128+l, 192+l (last predicated)
    int r0 = xr[lane];
    int r1 = xr[64 + lane];
    int r2 = xr[128 + lane];
    int r3 = (192 + lane < T_TOK) ? xr[192 + lane] : 0;

    float ax = 0.f, ay = 0.f, bx = 0.f, by = 0.f;

    for (int base = 0; base < len; base += 64) {
        int r = r0;
        if (base == 64)  r = r1;
        if (base == 128) r = r2;
        if (base == 192) r = r3;
        int m = len - base;
        if (m > 64) m = 64;

        for (int k = 0; k < m; k += 8) {
            const float2* rows[8];
#pragma unroll
            for (int j = 0; j < 8; ++j) {
                int idx = __shfl(r, (k + j) & 63);   // wave-uniform broadcast
                rows[j] = (const float2*)(emb + (size_t)idx * EMB);
            }
            float2 v[8];
#pragma unroll
            for (int j = 0; j < 8; ++j) v[j] = rows[j][lane];
#pragma unroll
            for (int j = 0; j < 8; ++j) {
                // k+j<m is wave-uniform -> cheap scalar predicate.
                // Loads beyond m fetch valid-but-unused rows (x holds real
                // vocab ids for all 200 slots) -- safe, just not accumulated.
                if (k + j < m) {
                    if (j & 1) { bx += v[j].x; by += v[j].y; }
                    else       { ax += v[j].x; ay += v[j].y; }
                }
            }
        }
    }

    const float inv = 1.0f / (float)len;
    float2 o;
    o.x = (ax + bx) * inv;
    o.y = (ay + by) * inv;
    ((float2*)(pooled + (size_t)n * EMB))[lane] = o;   // coalesced 8B/lane
}

// ---------------- Fused MLP: 8 samples per block ----------------
// S_TILE=8 -> grid 512 -> 2 blocks/CU -> 8 waves/CU (vs 4 before).
// Activations in LDS, +4-float padded stride; act reads are wave-uniform
// broadcasts (conflict-free, verified SQ_LDS_BANK_CONFLICT=0).
#define LPAD 4

template <int FIN, int FOUT, bool RELU>
__device__ __forceinline__ void layer(const float* __restrict__ sin,
                                      float* __restrict__ sout,
                                      const float* __restrict__ W,
                                      const float* __restrict__ b, int tid)
{
    constexpr int SIN_STR  = FIN + LPAD;
    constexpr int SOUT_STR = FOUT + LPAD;
    constexpr int OPT    = (FOUT > 256) ? (FOUT / 256) : 1; // out cols / thread
    constexpr int NO     = FOUT / OPT;                      // threads per sample-group
    constexpr int GROUPS = 256 / NO;
    constexpr int SPT    = S_TILE / GROUPS;                 // samples / thread

    const int o0 = (tid % NO) * OPT;
    const int s0 = (tid / NO) * SPT;

    float acc[OPT][SPT];
#pragma unroll
    for (int i = 0; i < OPT; ++i) {
        float bi = b[o0 + i];
#pragma unroll
        for (int j = 0; j < SPT; ++j) acc[i][j] = bi;
    }

    const float* wrow[OPT];
#pragma unroll
    for (int i = 0; i < OPT; ++i) wrow[i] = W + (size_t)(o0 + i) * FIN;

    for (int f = 0; f < FIN; f += 4) {
        float4 w[OPT];
#pragma unroll
        for (int i = 0; i < OPT; ++i)
            w[i] = *(const float4*)(wrow[i] + f);
#pragma unroll
        for (int j = 0; j < SPT; ++j) {
            float4 xv = *(const float4*)&sin[(s0 + j) * SIN_STR + f];
#pragma unroll
            for (int i = 0; i < OPT; ++i) {
                acc[i][j] = fmaf(xv.x, w[i].x, acc[i][j]);
                acc[i][j] = fmaf(xv.y, w[i].y, acc[i][j]);
                acc[i][j] = fmaf(xv.z, w[i].z, acc[i][j]);
                acc[i][j] = fmaf(xv.w, w[i].w, acc[i][j]);
            }
        }
    }

#pragma unroll
    for (int j = 0; j < SPT; ++j) {
#pragma unroll
        for (int i = 0; i < OPT; ++i) {
            float v = acc[i][j];
            if (RELU) v = fmaxf(v, 0.f);
            sout[(s0 + j) * SOUT_STR + (o0 + i)] = v;
        }
    }
}

__global__ __launch_bounds__(256) void mlp_kernel(
    const float* __restrict__ pooled,
    const float* __restrict__ W1, const float* __restrict__ b1,
    const float* __restrict__ W2, const float* __restrict__ b2,
    const float* __restrict__ W3, const float* __restrict__ b3,
    const float* __restrict__ W4, const float* __restrict__ b4,
    float* __restrict__ out)
{
    // bufA: X (stride 132, 8*132=1056) then H2 (stride 260, 8*260=2080)
    // bufB: H1 (stride 516, 8*516=4128) then H3 (stride 132, 1056)
    __shared__ float bufA[S_TILE * (256 + LPAD)];
    __shared__ float bufB[S_TILE * (512 + LPAD)];

    const int tid  = threadIdx.x;
    const int base = blockIdx.x * S_TILE;

    // Load pooled tile into LDS (padded stride 132)
    for (int idx = tid; idx < S_TILE * EMB; idx += 256) {
        int s = idx >> 7;
        int f = idx & 127;
        bufA[s * (EMB + LPAD) + f] = pooled[(size_t)(base + s) * EMB + f];
    }
    __syncthreads();

    layer<128, 512, true>(bufA, bufB, W1, b1, tid);
    __syncthreads();
    layer<512, 256, true>(bufB, bufA, W2, b2, tid);
    __syncthreads();
    layer<256, 128, true>(bufA, bufB, W3, b3, tid);
    __syncthreads();

    // Final layer: 128 -> 2
    if (tid < 2 * S_TILE) {
        int s = tid >> 1;
        int o = tid & 1;
        float accv = b4[o];
        const float* xr = &bufB[s * (EMB + LPAD)];
        const float* wr = &W4[(size_t)o * EMB];
#pragma unroll 8
        for (int f = 0; f < EMB; ++f) accv = fmaf(xr[f], wr[f], accv);
        out[(size_t)(base + s) * 2 + o] = accv;
    }
}

extern "C" void kernel_launch(void* const* d_in, const int* in_sizes, int n_in,
                              void* d_out, int out_size, void* d_ws, size_t ws_size,
                              hipStream_t stream)
{
    const int*   x       = (const int*)d_in[0];
    const int*   lengths = (const int*)d_in[1];
    const float* emb     = (const float*)d_in[2];
    const float* W1      = (const float*)d_in[3];
    const float* b1      = (const float*)d_in[4];
    const float* W2      = (const float*)d_in[5];
    const float* b2      = (const float*)d_in[6];
    const float* W3      = (const float*)d_in[7];
    const float* b3      = (const float*)d_in[8];
    const float* W4      = (const float*)d_in[9];
    const float* b4      = (const float*)d_in[10];
    float*       out     = (float*)d_out;

    const int N = in_sizes[1];           // 4096
    float* pooled = (float*)d_ws;        // N*128 floats = 2 MB

    pool_kernel<<<N / 4, 256, 0, stream>>>(x, lengths, emb, pooled);
    mlp_kernel<<<N / S_TILE, 256, 0, stream>>>(pooled, W1, b1, W2, b2, W3, b3,
                                               W4, b4, out);
}

// Round 3
// 189.690 us; speedup vs baseline: 1.2017x; 1.0262x over previous
//
#include <hip/hip_runtime.h>

#define T_TOK 200
#define EMB   128
#define S_TILE 8
#define LPAD  4

// ---------------- Fused pool + MLP ----------------
// Block = 256 threads = 4 waves, 8 samples/block, grid 512 (2 blocks/CU).
//
// Pool phase: wave w pools samples 2w and 2w+1 (sequentially). Row loads are
// float4/lane with 32 lanes per row -> one global_load_dwordx4 fetches TWO
// 512B embedding rows (half-wave 0 = even token, half-wave 1 = odd token).
// 8 loads (16 rows, 8KB) in flight per wave. Token indices preloaded into 4
// regs/lane, broadcast via __shfl (no idx->row memory dependency).
// Result written directly to LDS (no global round-trip).
//
// MLP phase: activations stay in LDS (padded stride, reads are same-address
// broadcasts); W streamed from global/L2 with explicit 1-step register
// prefetch in the f-loop.

template <int FIN, int FOUT, bool RELU>
__device__ __forceinline__ void layer(const float* __restrict__ sin,
                                      float* __restrict__ sout,
                                      const float* __restrict__ W,
                                      const float* __restrict__ b, int tid)
{
    constexpr int SIN_STR  = FIN + LPAD;
    constexpr int SOUT_STR = FOUT + LPAD;
    constexpr int OPT    = (FOUT > 256) ? (FOUT / 256) : 1;
    constexpr int NO     = FOUT / OPT;
    constexpr int GROUPS = 256 / NO;
    constexpr int SPT    = S_TILE / GROUPS;

    const int o0 = (tid % NO) * OPT;
    const int s0 = (tid / NO) * SPT;

    float acc[OPT][SPT];
#pragma unroll
    for (int i = 0; i < OPT; ++i) {
        float bi = b[o0 + i];
#pragma unroll
        for (int j = 0; j < SPT; ++j) acc[i][j] = bi;
    }

    const float* wr[OPT];
#pragma unroll
    for (int i = 0; i < OPT; ++i) wr[i] = W + (size_t)(o0 + i) * FIN;

    // 1-step register prefetch of W; acts are LDS broadcasts (cheap).
    float4 wc[OPT];
#pragma unroll
    for (int i = 0; i < OPT; ++i) wc[i] = *(const float4*)(wr[i]);

    int f = 0;
#pragma unroll 4
    for (; f < FIN - 4; f += 4) {
        float4 wn[OPT];
#pragma unroll
        for (int i = 0; i < OPT; ++i)
            wn[i] = *(const float4*)(wr[i] + f + 4);
#pragma unroll
        for (int j = 0; j < SPT; ++j) {
            float4 xv = *(const float4*)&sin[(s0 + j) * SIN_STR + f];
#pragma unroll
            for (int i = 0; i < OPT; ++i) {
                acc[i][j] = fmaf(xv.x, wc[i].x, acc[i][j]);
                acc[i][j] = fmaf(xv.y, wc[i].y, acc[i][j]);
                acc[i][j] = fmaf(xv.z, wc[i].z, acc[i][j]);
                acc[i][j] = fmaf(xv.w, wc[i].w, acc[i][j]);
            }
        }
#pragma unroll
        for (int i = 0; i < OPT; ++i) wc[i] = wn[i];
    }
    // last f-chunk
#pragma unroll
    for (int j = 0; j < SPT; ++j) {
        float4 xv = *(const float4*)&sin[(s0 + j) * SIN_STR + f];
#pragma unroll
        for (int i = 0; i < OPT; ++i) {
            acc[i][j] = fmaf(xv.x, wc[i].x, acc[i][j]);
            acc[i][j] = fmaf(xv.y, wc[i].y, acc[i][j]);
            acc[i][j] = fmaf(xv.z, wc[i].z, acc[i][j]);
            acc[i][j] = fmaf(xv.w, wc[i].w, acc[i][j]);
        }
    }

#pragma unroll
    for (int j = 0; j < SPT; ++j) {
#pragma unroll
        for (int i = 0; i < OPT; ++i) {
            float v = acc[i][j];
            if (RELU) v = fmaxf(v, 0.f);
            sout[(s0 + j) * SOUT_STR + (o0 + i)] = v;
        }
    }
}

__global__ __launch_bounds__(256) void fused_kernel(
    const int* __restrict__ x, const int* __restrict__ lengths,
    const float* __restrict__ emb,
    const float* __restrict__ W1, const float* __restrict__ b1,
    const float* __restrict__ W2, const float* __restrict__ b2,
    const float* __restrict__ W3, const float* __restrict__ b3,
    const float* __restrict__ W4, const float* __restrict__ b4,
    float* __restrict__ out)
{
    // bufA: X (stride 132) then H2 (stride 260); bufB: H1 (stride 516) then H3 (stride 132)
    __shared__ float bufA[S_TILE * (256 + LPAD)];
    __shared__ float bufB[S_TILE * (512 + LPAD)];

    const int tid  = threadIdx.x;
    const int wid  = tid >> 6;
    const int lane = tid & 63;
    const int base = blockIdx.x * S_TILE;
    const int half = lane >> 5;          // 0 = even-token row, 1 = odd-token row
    const int col4 = (lane & 31) * 4;    // this lane's 4 columns

    // ---- pool phase: wave wid pools samples 2*wid, 2*wid+1 ----
    for (int sl = 0; sl < 2; ++sl) {
        const int s   = wid * 2 + sl;
        const int n   = base + s;
        const int len = lengths[n];
        const int* xr = x + (size_t)n * T_TOK;

        // preload token indices: lane l holds tokens l, 64+l, 128+l, 192+l (clamped)
        int r0 = xr[lane];
        int r1 = xr[64 + lane];
        int r2 = xr[128 + lane];
        int r3 = xr[(192 + lane < T_TOK) ? (192 + lane) : (T_TOK - 1)];

        float4 acc = make_float4(0.f, 0.f, 0.f, 0.f);

        for (int c = 0; c < 4; ++c) {
            const int coff = c * 64;
            if (coff >= len) break;
            int m = len - coff;
            if (m > 64) m = 64;
            int r = r0;
            if (c == 1) r = r1;
            if (c == 2) r = r2;
            if (c == 3) r = r3;

            for (int k = 0; k < m; k += 16) {   // 16 rows per batch, 8 loads
                float4 v[8];
#pragma unroll
                for (int i = 0; i < 8; ++i) {
                    int t   = k + 2 * i + half;          // <= 63 (k <= 48)
                    int idx = __shfl(r, t);              // valid vocab id always
                    v[i] = *(const float4*)(emb + (size_t)idx * EMB + col4);
                }
#pragma unroll
                for (int i = 0; i < 8; ++i) {
                    int T = coff + k + 2 * i + half;
                    if (T < len) {
                        acc.x += v[i].x; acc.y += v[i].y;
                        acc.z += v[i].z; acc.w += v[i].w;
                    }
                }
            }
        }

        // combine even/odd half-wave partial sums
        acc.x += __shfl(acc.x, lane ^ 32);
        acc.y += __shfl(acc.y, lane ^ 32);
        acc.z += __shfl(acc.z, lane ^ 32);
        acc.w += __shfl(acc.w, lane ^ 32);

        if (half == 0) {
            const float inv = 1.0f / (float)len;
            float4 o = make_float4(acc.x * inv, acc.y * inv, acc.z * inv, acc.w * inv);
            *(float4*)&bufA[s * (EMB + LPAD) + col4] = o;
        }
    }
    __syncthreads();

    // ---- MLP phase ----
    layer<128, 512, true>(bufA, bufB, W1, b1, tid);
    __syncthreads();
    layer<512, 256, true>(bufB, bufA, W2, b2, tid);
    __syncthreads();
    layer<256, 128, true>(bufA, bufB, W3, b3, tid);
    __syncthreads();

    if (tid < 2 * S_TILE) {
        int s = tid >> 1;
        int o = tid & 1;
        float accv = b4[o];
        const float* xr2 = &bufB[s * (EMB + LPAD)];
        const float* wr2 = &W4[(size_t)o * EMB];
#pragma unroll 8
        for (int f = 0; f < EMB; ++f) accv = fmaf(xr2[f], wr2[f], accv);
        out[(size_t)(base + s) * 2 + o] = accv;
    }
}

extern "C" void kernel_launch(void* const* d_in, const int* in_sizes, int n_in,
                              void* d_out, int out_size, void* d_ws, size_t ws_size,
                              hipStream_t stream)
{
    const int*   x       = (const int*)d_in[0];
    const int*   lengths = (const int*)d_in[1];
    const float* emb     = (const float*)d_in[2];
    const float* W1      = (const float*)d_in[3];
    const float* b1      = (const float*)d_in[4];
    const float* W2      = (const float*)d_in[5];
    const float* b2      = (const float*)d_in[6];
    const float* W3      = (const float*)d_in[7];
    const float* b3      = (const float*)d_in[8];
    const float* W4      = (const float*)d_in[9];
    const float* b4      = (const float*)d_in[10];
    float*       out     = (float*)d_out;

    const int N = in_sizes[1];   // 4096
    fused_kernel<<<N / S_TILE, 256, 0, stream>>>(x, lengths, emb,
                                                 W1, b1, W2, b2, W3, b3, W4, b4,
                                                 out);
}